// Round 17
// baseline (1468.000 us; speedup 1.0000x reference)
//
#include <hip/hip_runtime.h>
#include <hip/hip_bf16.h>

#define K_TAPS 27
#define DCH 64
#define BN_EPS 1e-5f
#define SCAN_CHUNK 4096

typedef float f32x4 __attribute__((ext_vector_type(4)));
typedef short bf16x8 __attribute__((ext_vector_type(8)));
typedef unsigned int uint;
typedef unsigned short ushort;

// pack two f32 -> one dword of 2 bf16 (RNE); same instruction everywhere so
// rounding/order is consistent across pre-packed and in-kernel conversions.
#define CVTPK(dst, lo, hi) \
    asm("v_cvt_pk_bf16_f32 %0, %1, %2" : "=v"(dst) : "v"(lo), "v"(hi))

// ---------------------------------------------------------------------------
// CSR build pass A (fused hist+rank): returning atomic per pair, coalesced
// packed write: packed[i] = (bucket << 11) | rank_within_bucket.
// ---------------------------------------------------------------------------
__global__ __launch_bounds__(256)
void rank_kernel(const int* __restrict__ pout, int P,
                 int* __restrict__ counts, uint* __restrict__ packed)
{
    const int k = blockIdx.y;
    const int p = blockIdx.x * 256 + threadIdx.x;
    if (p < P) {
        const size_t i = (size_t)k * P + p;
        const int b = pout[i] * K_TAPS + k;
        const int r = atomicAdd(&counts[b], 1);
        packed[i] = ((uint)b << 11) | (uint)(r & 2047);
    }
}

__global__ __launch_bounds__(256)
void scan_sum_kernel(const int* __restrict__ counts, int n, int* __restrict__ partials)
{
    __shared__ int sm[256];
    const int base = blockIdx.x * SCAN_CHUNK;
    int s = 0;
#pragma unroll
    for (int j = 0; j < 16; ++j) {
        const int i = base + j * 256 + threadIdx.x;
        if (i < n) s += counts[i];
    }
    sm[threadIdx.x] = s;
    __syncthreads();
    for (int off = 128; off > 0; off >>= 1) {
        if (threadIdx.x < off) sm[threadIdx.x] += sm[threadIdx.x + off];
        __syncthreads();
    }
    if (threadIdx.x == 0) partials[blockIdx.x] = sm[0];
}

__global__ __launch_bounds__(512)
void scan_partials_kernel(int* __restrict__ partials, int n)
{
    __shared__ int sm[512];
    const int t = threadIdx.x;
    const int v = (t < n) ? partials[t] : 0;
    sm[t] = v;
    __syncthreads();
    for (int off = 1; off < 512; off <<= 1) {
        int tv = 0;
        if (t >= off) tv = sm[t - off];
        __syncthreads();
        if (t >= off) sm[t] += tv;
        __syncthreads();
    }
    if (t < n) partials[t] = sm[t] - v;  // exclusive
}

// S[i] = exclusive prefix (bucket start); S[n] = total.
__global__ __launch_bounds__(256)
void scan_write_kernel(const int* __restrict__ counts, int n,
                       const int* __restrict__ chunkoff, int* __restrict__ S)
{
    __shared__ int sm[256];
    const int base = blockIdx.x * SCAN_CHUNK + threadIdx.x * 16;
    int v[16];
    int s = 0;
#pragma unroll
    for (int j = 0; j < 16; ++j) {
        const int i = base + j;
        v[j] = (i < n) ? counts[i] : 0;
        s += v[j];
    }
    sm[threadIdx.x] = s;
    __syncthreads();
    for (int off = 1; off < 256; off <<= 1) {
        int tv = 0;
        if (threadIdx.x >= off) tv = sm[threadIdx.x - off];
        __syncthreads();
        if (threadIdx.x >= off) sm[threadIdx.x] += tv;
        __syncthreads();
    }
    int run = chunkoff[blockIdx.x] + sm[threadIdx.x] - s;  // exclusive base
#pragma unroll
    for (int j = 0; j < 16; ++j) {
        const int i = base + j;
        if (i < n) {
            S[i] = run;
            run += v[j];
            if (i == n - 1) S[n] = run;
        }
    }
}

// CSR build pass B (atomic-free scatter): E[S[b] + rank] = pin[i]
__global__ __launch_bounds__(256)
void scatter_kernel(const int* __restrict__ pin, const uint* __restrict__ packed,
                    int P, const int* __restrict__ S, int* __restrict__ E)
{
    const int k = blockIdx.y;
    const int p = blockIdx.x * 256 + threadIdx.x;
    if (p < P) {
        const size_t i = (size_t)k * P + p;
        const uint u = packed[i];
        E[S[u >> 11] + (int)(u & 2047u)] = pin[i];
    }
}

// ---------------------------------------------------------------------------
// W pre-pack into MFMA B-fragment layout, bf16 (CVTPK).
// Wp[k][kc][nt][lane][4 dwords]. blocks 0..26 Wd(C=32), 27..53 W1, 54..80 W2.
// ---------------------------------------------------------------------------
__global__ __launch_bounds__(256)
void pack_w_kernel(const float* __restrict__ Wd,
                   const float* __restrict__ W1,
                   const float* __restrict__ W2,
                   uint* __restrict__ Pd, uint* __restrict__ P1, uint* __restrict__ P2)
{
    int b = blockIdx.x;
    const float* W; uint* P; int C, k;
    if (b < 27)      { W = Wd; P = Pd; C = 32; k = b; }
    else if (b < 54) { W = W1; P = P1; C = 64; k = b - 27; }
    else             { W = W2; P = P2; C = 64; k = b - 54; }
    const int KC = C / 32;
    for (int t = threadIdx.x; t < KC * 4 * 64; t += 256) {
        const int l  = t & 63;
        const int nt = (t >> 6) & 3;
        const int kc = t >> 8;
        const int c0  = kc * 32 + ((l >> 4) << 3);
        const int col = nt * 16 + (l & 15);
        float f[8];
#pragma unroll
        for (int j = 0; j < 8; ++j)
            f[j] = W[((size_t)k * C + c0 + j) * DCH + col];
        uint4 u;
        CVTPK(u.x, f[0], f[1]);
        CVTPK(u.y, f[2], f[3]);
        CVTPK(u.z, f[4], f[5]);
        CVTPK(u.w, f[6], f[7]);
        *reinterpret_cast<uint4*>(P + ((size_t)((k * KC + kc) * 4 + nt) * 64 + l) * 4) = u;
    }
}

// fp32 -> packed bf16 (pairwise CVTPK, identical rounding to conv path)
__global__ __launch_bounds__(256)
void f2bf_kernel(const float* __restrict__ in, uint* __restrict__ out, int n_half)
{
    for (int i = blockIdx.x * 256 + threadIdx.x; i < n_half; i += gridDim.x * 256) {
        const float2 v = reinterpret_cast<const float2*>(in)[i];
        uint u;
        CVTPK(u, v.x, v.y);
        out[i] = u;
    }
}

// ---------------------------------------------------------------------------
// Implicit-GEMM gather conv, v5: r15 structure (2-wave k-split, slot
// UNROLL-2) with __launch_bounds__(128, 8) -- occupancy raised via MORE
// RESIDENT WAVES instead of more per-wave chains (r16's unroll-4 spilled:
// 521MB scratch WRITE_SIZE). VGPR budget 64 >= the 36 actually used.
// ---------------------------------------------------------------------------
template <int C, typename T>
__global__ __launch_bounds__(128, 8)
void mfma_conv_kernel(const T* __restrict__ x,
                      const uint* __restrict__ Wp,
                      const int* __restrict__ S,
                      const int* __restrict__ E,
                      float* __restrict__ y,
                      float* __restrict__ stats,
                      int n_out)
{
    constexpr int KC = C / 32;
    constexpr int SN = 16 * K_TAPS + 1;   // 433
    const int tid  = threadIdx.x;
    const int lane = tid & 63;
    const int wave = tid >> 6;            // 0,1
    const int r0 = blockIdx.x * 16;
    if (r0 >= n_out) return;

    __shared__ int sS[SN];
    __shared__ f32x4 red[2][4][64];

    for (int i = tid; i < SN; i += 128) sS[i] = S[r0 * K_TAPS + i];
    __syncthreads();

    const int l15  = lane & 15;
    const int kgrp = lane >> 4;
    const int koff = kgrp * 8;

    f32x4 acc[4];
#pragma unroll
    for (int nt = 0; nt < 4; ++nt) acc[nt] = (f32x4)0.f;

    for (int k = wave; k < K_TAPS; k += 2) {
        bf16x8 B[KC][4];
#pragma unroll
        for (int kc = 0; kc < KC; ++kc)
#pragma unroll
            for (int nt = 0; nt < 4; ++nt)
                B[kc][nt] = *reinterpret_cast<const bf16x8*>(
                    Wp + ((size_t)((k * KC + kc) * 4 + nt) * 64 + lane) * 4);

        const int e1 = sS[l15 * K_TAPS + k + 1];
        for (int s = sS[l15 * K_TAPS + k]; ; s += 2) {
            const bool a0 = s < e1;
            const bool a1 = s + 1 < e1;
            if (!__any(a0)) break;
            // issue both E loads, then both gathers (2 chains in flight)
            const int ir0 = a0 ? E[s] : 0;
            const int ir1 = a1 ? E[s + 1] : 0;
            bf16x8 A0[KC], A1[KC];
#pragma unroll
            for (int kc = 0; kc < KC; ++kc) {
                if constexpr (sizeof(T) == 2) {
                    bf16x8 v0 = (bf16x8)0, v1 = (bf16x8)0;
                    if (a0) v0 = *reinterpret_cast<const bf16x8*>(
                        (const ushort*)x + (size_t)ir0 * C + kc * 32 + koff);
                    if (a1) v1 = *reinterpret_cast<const bf16x8*>(
                        (const ushort*)x + (size_t)ir1 * C + kc * 32 + koff);
                    A0[kc] = v0;
                    A1[kc] = v1;
                } else {
                    float4 f0 = {0.f, 0.f, 0.f, 0.f}, f1 = {0.f, 0.f, 0.f, 0.f};
                    float4 g0 = {0.f, 0.f, 0.f, 0.f}, g1 = {0.f, 0.f, 0.f, 0.f};
                    if (a0) {
                        const float4* fp = reinterpret_cast<const float4*>(
                            (const float*)x + (size_t)ir0 * C + kc * 32 + koff);
                        f0 = fp[0];
                        f1 = fp[1];
                    }
                    if (a1) {
                        const float4* gp = reinterpret_cast<const float4*>(
                            (const float*)x + (size_t)ir1 * C + kc * 32 + koff);
                        g0 = gp[0];
                        g1 = gp[1];
                    }
                    uint4 u, w;
                    CVTPK(u.x, f0.x, f0.y);
                    CVTPK(u.y, f0.z, f0.w);
                    CVTPK(u.z, f1.x, f1.y);
                    CVTPK(u.w, f1.z, f1.w);
                    CVTPK(w.x, g0.x, g0.y);
                    CVTPK(w.y, g0.z, g0.w);
                    CVTPK(w.z, g1.x, g1.y);
                    CVTPK(w.w, g1.z, g1.w);
                    A0[kc] = *reinterpret_cast<bf16x8*>(&u);
                    A1[kc] = *reinterpret_cast<bf16x8*>(&w);
                }
            }
#pragma unroll
            for (int kc = 0; kc < KC; ++kc)
#pragma unroll
                for (int nt = 0; nt < 4; ++nt)
                    acc[nt] = __builtin_amdgcn_mfma_f32_16x16x32_bf16(
                        A0[kc], B[kc][nt], acc[nt], 0, 0, 0);
#pragma unroll
            for (int kc = 0; kc < KC; ++kc)
#pragma unroll
                for (int nt = 0; nt < 4; ++nt)
                    acc[nt] = __builtin_amdgcn_mfma_f32_16x16x32_bf16(
                        A1[kc], B[kc][nt], acc[nt], 0, 0, 0);
        }
    }

    // cross-wave reduce + epilogue (wave w handles ntiles 2w, 2w+1)
#pragma unroll
    for (int nt = 0; nt < 4; ++nt) red[wave][nt][lane] = acc[nt];
    __syncthreads();

#pragma unroll
    for (int t = 0; t < 2; ++t) {
        const int nt = wave * 2 + t;
        const f32x4 v4 = red[0][nt][lane] + red[1][nt][lane];
        const int col = nt * 16 + l15;
        float sum = 0.f, ssum = 0.f;
#pragma unroll
        for (int j = 0; j < 4; ++j) {
            const float v = v4[j];
            y[(size_t)(r0 + kgrp * 4 + j) * DCH + col] = v;
            sum += v;
            ssum += v * v;
        }
        sum  += __shfl_xor(sum, 16);  sum  += __shfl_xor(sum, 32);
        ssum += __shfl_xor(ssum, 16); ssum += __shfl_xor(ssum, 32);
        if (kgrp == 0) {
            unsafeAtomicAdd(&stats[col], sum);
            unsafeAtomicAdd(&stats[64 + col], ssum);
        }
    }
}

// BN+ReLU in place; optionally also emit packed-bf16 copy (CVTPK rounding).
template <bool WB>
__global__ __launch_bounds__(256)
void bn_apply_kernel(float* __restrict__ x, uint* __restrict__ xb, int n_half,
                     const float* __restrict__ stats,
                     const float* __restrict__ g,
                     const float* __restrict__ b,
                     float inv_n)
{
    const int d0 = (threadIdx.x * 2) & 63;
    const float m0 = stats[d0] * inv_n,     m1 = stats[d0 + 1] * inv_n;
    const float v0 = stats[64 + d0] * inv_n - m0 * m0;
    const float v1 = stats[64 + d0 + 1] * inv_n - m1 * m1;
    const float sc0 = g[d0] * rsqrtf(v0 + BN_EPS), sc1 = g[d0 + 1] * rsqrtf(v1 + BN_EPS);
    const float sh0 = b[d0] - m0 * sc0,            sh1 = b[d0 + 1] - m1 * sc1;
    for (int i = blockIdx.x * 256 + threadIdx.x; i < n_half; i += gridDim.x * 256) {
        float2 v = reinterpret_cast<float2*>(x)[i];
        const float r0 = fmaxf(__builtin_fmaf(v.x, sc0, sh0), 0.f);
        const float r1 = fmaxf(__builtin_fmaf(v.y, sc1, sh1), 0.f);
        reinterpret_cast<float2*>(x)[i] = make_float2(r0, r1);
        if (WB) {
            uint u;
            CVTPK(u, r0, r1);
            xb[i] = u;
        }
    }
}

__global__ __launch_bounds__(256)
void bn_final_kernel(float* __restrict__ y2, const float* __restrict__ xnet,
                     int n_elem,
                     const float* __restrict__ stats,
                     const float* __restrict__ g,
                     const float* __restrict__ b,
                     float inv_n)
{
    const int d = threadIdx.x & 63;
    const float m   = stats[d] * inv_n;
    const float var = stats[64 + d] * inv_n - m * m;
    const float sc  = g[d] * rsqrtf(var + BN_EPS);
    const float sh  = b[d] - m * sc;
    for (int i = blockIdx.x * 256 + threadIdx.x; i < n_elem; i += gridDim.x * 256) {
        float v = y2[i];
        y2[i] = xnet[i] + fmaxf(__builtin_fmaf(v, sc, sh), 0.f);
    }
}

extern "C" void kernel_launch(void* const* d_in, const int* in_sizes, int n_in,
                              void* d_out, int out_size, void* d_ws, size_t ws_size,
                              hipStream_t stream)
{
    const float* feats  = (const float*)d_in[0];
    const float* W_down = (const float*)d_in[1];
    const float* g0     = (const float*)d_in[2];
    const float* b0     = (const float*)d_in[3];
    const float* W1     = (const float*)d_in[4];
    const float* g1     = (const float*)d_in[5];
    const float* b1     = (const float*)d_in[6];
    const float* W2     = (const float*)d_in[7];
    const float* g2     = (const float*)d_in[8];
    const float* b2     = (const float*)d_in[9];
    const int* pdi      = (const int*)d_in[10];
    const int* pdo      = (const int*)d_in[11];
    const int* psi      = (const int*)d_in[12];
    const int* pso      = (const int*)d_in[13];

    const int P1     = in_sizes[10] / K_TAPS;
    const int P2     = in_sizes[12] / K_TAPS;
    const int M1     = in_sizes[10];
    const int Nin    = in_sizes[0] / 32;
    const int n_out  = out_size / DCH;
    const int n_elem = n_out * DCH;
    const int NB     = n_out * K_TAPS;
    const float inv_n = 1.0f / (float)n_out;

    float* out = (float*)d_out;

    // ---- workspace layout (base ~29.6 MB, r13-proven) ----
    float* xnet  = (float*)d_ws;
    int*   counts = (int*)d_ws;
    uint*  rank_sm = (uint*)d_ws + NB;
    float* stats = xnet + (size_t)n_elem;
    int* S = (int*)(stats + 384);
    int* E = S + (NB + 1);
    int* partials = E + M1;              // M1 >= M2
    uint* Wp_dn = (uint*)(partials + 1024);
    uint* Wp_s1 = Wp_dn + 27 * 1 * 4 * 64 * 4;
    uint* Wp_s2 = Wp_s1 + 27 * 2 * 4 * 64 * 4;
    uint* rank_dn = (uint*)d_out;

    // optional bf16-input extension (gated on ws_size)
    uintptr_t pa = (uintptr_t)(Wp_s2 + 27 * 2 * 4 * 64 * 4);
    pa = (pa + 255) & ~(uintptr_t)255;
    uint* featsb = (uint*)pa;                       // Nin*32 bf16 = Nin*16 uints
    uint* x0b    = featsb + (size_t)Nin * 16;       // n_elem/2 uints
    uint* xnetb  = x0b + (size_t)n_elem / 2;        // n_elem/2 uints
    const size_t needed = (size_t)((char*)(xnetb + n_elem / 2) - (char*)d_ws);
    const bool bf16path = ws_size >= needed;

    float* st0 = stats;
    float* st1 = stats + 128;
    float* st2 = stats + 256;

    const dim3 blk(256);
    const dim3 cblk(128);
    const dim3 gridH1((P1 + 255) / 256, K_TAPS);
    const dim3 gridH2((P2 + 255) / 256, K_TAPS);
    const int nchunks = (NB + SCAN_CHUNK - 1) / SCAN_CHUNK;
    const int ewBlocks = 2048;
    const int convBlocks = (n_out + 15) / 16;   // 16 rows/block, 2 waves k-split

    hipMemsetAsync(stats, 0, sizeof(float) * 384, stream);

    // ---- W fragment pre-pack ----
    pack_w_kernel<<<81, blk, 0, stream>>>(W_down, W1, W2, Wp_dn, Wp_s1, Wp_s2);
    if (bf16path)
        f2bf_kernel<<<ewBlocks, blk, 0, stream>>>(feats, featsb, Nin * 16);

    // ---- build down CSR: rank -> scan -> scatter ----
    hipMemsetAsync(counts, 0, sizeof(int) * (size_t)NB, stream);
    rank_kernel<<<gridH1, blk, 0, stream>>>(pdo, P1, counts, rank_dn);
    scan_sum_kernel<<<nchunks, blk, 0, stream>>>(counts, NB, partials);
    scan_partials_kernel<<<1, 512, 0, stream>>>(partials, nchunks);
    scan_write_kernel<<<nchunks, blk, 0, stream>>>(counts, NB, partials, S);
    scatter_kernel<<<gridH1, blk, 0, stream>>>(pdi, rank_dn, P1, S, E);

    // ---- DownBlock ----
    if (bf16path)
        mfma_conv_kernel<32, ushort><<<convBlocks, cblk, 0, stream>>>(
            (const ushort*)featsb, Wp_dn, S, E, out, st0, n_out);
    else
        mfma_conv_kernel<32, float><<<convBlocks, cblk, 0, stream>>>(
            feats, Wp_dn, S, E, out, st0, n_out);
    if (bf16path)
        bn_apply_kernel<true><<<ewBlocks, blk, 0, stream>>>(out, x0b, n_elem / 2, st0, g0, b0, inv_n);
    else
        bn_apply_kernel<false><<<ewBlocks, blk, 0, stream>>>(out, nullptr, n_elem / 2, st0, g0, b0, inv_n);

    // ---- build subm CSR (down CSR dead) ----
    hipMemsetAsync(counts, 0, sizeof(int) * (size_t)NB, stream);
    rank_kernel<<<gridH2, blk, 0, stream>>>(pso, P2, counts, rank_sm);
    scan_sum_kernel<<<nchunks, blk, 0, stream>>>(counts, NB, partials);
    scan_partials_kernel<<<1, 512, 0, stream>>>(partials, nchunks);
    scan_write_kernel<<<nchunks, blk, 0, stream>>>(counts, NB, partials, S);
    scatter_kernel<<<gridH2, blk, 0, stream>>>(psi, rank_sm, P2, S, E);

    // ---- ResBlock conv1 ----
    if (bf16path)
        mfma_conv_kernel<64, ushort><<<convBlocks, cblk, 0, stream>>>(
            (const ushort*)x0b, Wp_s1, S, E, xnet, st1, n_out);
    else
        mfma_conv_kernel<64, float><<<convBlocks, cblk, 0, stream>>>(
            out, Wp_s1, S, E, xnet, st1, n_out);
    if (bf16path)
        bn_apply_kernel<true><<<ewBlocks, blk, 0, stream>>>(xnet, xnetb, n_elem / 2, st1, g1, b1, inv_n);
    else
        bn_apply_kernel<false><<<ewBlocks, blk, 0, stream>>>(xnet, nullptr, n_elem / 2, st1, g1, b1, inv_n);

    // ---- ResBlock conv2 ----
    if (bf16path)
        mfma_conv_kernel<64, ushort><<<convBlocks, cblk, 0, stream>>>(
            (const ushort*)xnetb, Wp_s2, S, E, out, st2, n_out);
    else
        mfma_conv_kernel<64, float><<<convBlocks, cblk, 0, stream>>>(
            xnet, Wp_s2, S, E, out, st2, n_out);

    // ---- out = x_net + relu(bn(y2)) ----
    bn_final_kernel<<<ewBlocks, blk, 0, stream>>>(out, xnet, n_elem, st2, g2, b2, inv_n);
}

// Round 18
// 671.286 us; speedup vs baseline: 2.1868x; 2.1868x over previous
//
#include <hip/hip_runtime.h>
#include <hip/hip_bf16.h>

#define K_TAPS 27
#define DCH 64
#define BN_EPS 1e-5f
#define SCAN_CHUNK 4096

typedef float f32x4 __attribute__((ext_vector_type(4)));
typedef short bf16x8 __attribute__((ext_vector_type(8)));
typedef unsigned int uint;
typedef unsigned short ushort;

// pack two f32 -> one dword of 2 bf16 (RNE); same instruction everywhere so
// rounding/order is consistent across pre-packed and in-kernel conversions.
#define CVTPK(dst, lo, hi) \
    asm("v_cvt_pk_bf16_f32 %0, %1, %2" : "=v"(dst) : "v"(lo), "v"(hi))

// ---------------------------------------------------------------------------
// CSR build pass A (fused hist+rank): returning atomic per pair, coalesced
// packed write: packed[i] = (bucket << 11) | rank_within_bucket.
// ---------------------------------------------------------------------------
__global__ __launch_bounds__(256)
void rank_kernel(const int* __restrict__ pout, int P,
                 int* __restrict__ counts, uint* __restrict__ packed)
{
    const int k = blockIdx.y;
    const int p = blockIdx.x * 256 + threadIdx.x;
    if (p < P) {
        const size_t i = (size_t)k * P + p;
        const int b = pout[i] * K_TAPS + k;
        const int r = atomicAdd(&counts[b], 1);
        packed[i] = ((uint)b << 11) | (uint)(r & 2047);
    }
}

__global__ __launch_bounds__(256)
void scan_sum_kernel(const int* __restrict__ counts, int n, int* __restrict__ partials)
{
    __shared__ int sm[256];
    const int base = blockIdx.x * SCAN_CHUNK;
    int s = 0;
#pragma unroll
    for (int j = 0; j < 16; ++j) {
        const int i = base + j * 256 + threadIdx.x;
        if (i < n) s += counts[i];
    }
    sm[threadIdx.x] = s;
    __syncthreads();
    for (int off = 128; off > 0; off >>= 1) {
        if (threadIdx.x < off) sm[threadIdx.x] += sm[threadIdx.x + off];
        __syncthreads();
    }
    if (threadIdx.x == 0) partials[blockIdx.x] = sm[0];
}

__global__ __launch_bounds__(512)
void scan_partials_kernel(int* __restrict__ partials, int n)
{
    __shared__ int sm[512];
    const int t = threadIdx.x;
    const int v = (t < n) ? partials[t] : 0;
    sm[t] = v;
    __syncthreads();
    for (int off = 1; off < 512; off <<= 1) {
        int tv = 0;
        if (t >= off) tv = sm[t - off];
        __syncthreads();
        if (t >= off) sm[t] += tv;
        __syncthreads();
    }
    if (t < n) partials[t] = sm[t] - v;  // exclusive
}

// S[i] = exclusive prefix (bucket start); S[n] = total.
__global__ __launch_bounds__(256)
void scan_write_kernel(const int* __restrict__ counts, int n,
                       const int* __restrict__ chunkoff, int* __restrict__ S)
{
    __shared__ int sm[256];
    const int base = blockIdx.x * SCAN_CHUNK + threadIdx.x * 16;
    int v[16];
    int s = 0;
#pragma unroll
    for (int j = 0; j < 16; ++j) {
        const int i = base + j;
        v[j] = (i < n) ? counts[i] : 0;
        s += v[j];
    }
    sm[threadIdx.x] = s;
    __syncthreads();
    for (int off = 1; off < 256; off <<= 1) {
        int tv = 0;
        if (threadIdx.x >= off) tv = sm[threadIdx.x - off];
        __syncthreads();
        if (threadIdx.x >= off) sm[threadIdx.x] += tv;
        __syncthreads();
    }
    int run = chunkoff[blockIdx.x] + sm[threadIdx.x] - s;  // exclusive base
#pragma unroll
    for (int j = 0; j < 16; ++j) {
        const int i = base + j;
        if (i < n) {
            S[i] = run;
            run += v[j];
            if (i == n - 1) S[n] = run;
        }
    }
}

// CSR build pass B (atomic-free scatter): E[S[b] + rank] = pin[i]
__global__ __launch_bounds__(256)
void scatter_kernel(const int* __restrict__ pin, const uint* __restrict__ packed,
                    int P, const int* __restrict__ S, int* __restrict__ E)
{
    const int k = blockIdx.y;
    const int p = blockIdx.x * 256 + threadIdx.x;
    if (p < P) {
        const size_t i = (size_t)k * P + p;
        const uint u = packed[i];
        E[S[u >> 11] + (int)(u & 2047u)] = pin[i];
    }
}

// ---------------------------------------------------------------------------
// W pre-pack into MFMA B-fragment layout, bf16 (CVTPK).
// Wp[k][kc][nt][lane][4 dwords]. blocks 0..26 Wd(C=32), 27..53 W1, 54..80 W2.
// ---------------------------------------------------------------------------
__global__ __launch_bounds__(256)
void pack_w_kernel(const float* __restrict__ Wd,
                   const float* __restrict__ W1,
                   const float* __restrict__ W2,
                   uint* __restrict__ Pd, uint* __restrict__ P1, uint* __restrict__ P2)
{
    int b = blockIdx.x;
    const float* W; uint* P; int C, k;
    if (b < 27)      { W = Wd; P = Pd; C = 32; k = b; }
    else if (b < 54) { W = W1; P = P1; C = 64; k = b - 27; }
    else             { W = W2; P = P2; C = 64; k = b - 54; }
    const int KC = C / 32;
    for (int t = threadIdx.x; t < KC * 4 * 64; t += 256) {
        const int l  = t & 63;
        const int nt = (t >> 6) & 3;
        const int kc = t >> 8;
        const int c0  = kc * 32 + ((l >> 4) << 3);
        const int col = nt * 16 + (l & 15);
        float f[8];
#pragma unroll
        for (int j = 0; j < 8; ++j)
            f[j] = W[((size_t)k * C + c0 + j) * DCH + col];
        uint4 u;
        CVTPK(u.x, f[0], f[1]);
        CVTPK(u.y, f[2], f[3]);
        CVTPK(u.z, f[4], f[5]);
        CVTPK(u.w, f[6], f[7]);
        *reinterpret_cast<uint4*>(P + ((size_t)((k * KC + kc) * 4 + nt) * 64 + l) * 4) = u;
    }
}

// fp32 -> packed bf16 (pairwise CVTPK, identical rounding to conv path)
__global__ __launch_bounds__(256)
void f2bf_kernel(const float* __restrict__ in, uint* __restrict__ out, int n_half)
{
    for (int i = blockIdx.x * 256 + threadIdx.x; i < n_half; i += gridDim.x * 256) {
        const float2 v = reinterpret_cast<const float2*>(in)[i];
        uint u;
        CVTPK(u, v.x, v.y);
        out[i] = u;
    }
}

// ---------------------------------------------------------------------------
// Implicit-GEMM gather conv, v5 (r15 structure, best measured: 665us total).
// 2-wave k-split, slot UNROLL-2, LB(128,5): the 102-reg budget covers the
// ~68 unified VGPR+AGPR live set; LB(128,8)/unroll-4 both spilled (r16/r17:
// acc AGPRs count against the unified file -> scratch storm).
// ---------------------------------------------------------------------------
template <int C, typename T>
__global__ __launch_bounds__(128, 5)
void mfma_conv_kernel(const T* __restrict__ x,
                      const uint* __restrict__ Wp,
                      const int* __restrict__ S,
                      const int* __restrict__ E,
                      float* __restrict__ y,
                      float* __restrict__ stats,
                      int n_out)
{
    constexpr int KC = C / 32;
    constexpr int SN = 16 * K_TAPS + 1;   // 433
    const int tid  = threadIdx.x;
    const int lane = tid & 63;
    const int wave = tid >> 6;            // 0,1
    const int r0 = blockIdx.x * 16;
    if (r0 >= n_out) return;

    __shared__ int sS[SN];
    __shared__ f32x4 red[2][4][64];

    for (int i = tid; i < SN; i += 128) sS[i] = S[r0 * K_TAPS + i];
    __syncthreads();

    const int l15  = lane & 15;
    const int kgrp = lane >> 4;
    const int koff = kgrp * 8;

    f32x4 acc[4];
#pragma unroll
    for (int nt = 0; nt < 4; ++nt) acc[nt] = (f32x4)0.f;

    for (int k = wave; k < K_TAPS; k += 2) {
        bf16x8 B[KC][4];
#pragma unroll
        for (int kc = 0; kc < KC; ++kc)
#pragma unroll
            for (int nt = 0; nt < 4; ++nt)
                B[kc][nt] = *reinterpret_cast<const bf16x8*>(
                    Wp + ((size_t)((k * KC + kc) * 4 + nt) * 64 + lane) * 4);

        const int e1 = sS[l15 * K_TAPS + k + 1];
        for (int s = sS[l15 * K_TAPS + k]; ; s += 2) {
            const bool a0 = s < e1;
            const bool a1 = s + 1 < e1;
            if (!__any(a0)) break;
            // issue both E loads, then both gathers (2 chains in flight)
            const int ir0 = a0 ? E[s] : 0;
            const int ir1 = a1 ? E[s + 1] : 0;
            bf16x8 A0[KC], A1[KC];
#pragma unroll
            for (int kc = 0; kc < KC; ++kc) {
                if constexpr (sizeof(T) == 2) {
                    bf16x8 v0 = (bf16x8)0, v1 = (bf16x8)0;
                    if (a0) v0 = *reinterpret_cast<const bf16x8*>(
                        (const ushort*)x + (size_t)ir0 * C + kc * 32 + koff);
                    if (a1) v1 = *reinterpret_cast<const bf16x8*>(
                        (const ushort*)x + (size_t)ir1 * C + kc * 32 + koff);
                    A0[kc] = v0;
                    A1[kc] = v1;
                } else {
                    float4 f0 = {0.f, 0.f, 0.f, 0.f}, f1 = {0.f, 0.f, 0.f, 0.f};
                    float4 g0 = {0.f, 0.f, 0.f, 0.f}, g1 = {0.f, 0.f, 0.f, 0.f};
                    if (a0) {
                        const float4* fp = reinterpret_cast<const float4*>(
                            (const float*)x + (size_t)ir0 * C + kc * 32 + koff);
                        f0 = fp[0];
                        f1 = fp[1];
                    }
                    if (a1) {
                        const float4* gp = reinterpret_cast<const float4*>(
                            (const float*)x + (size_t)ir1 * C + kc * 32 + koff);
                        g0 = gp[0];
                        g1 = gp[1];
                    }
                    uint4 u, w;
                    CVTPK(u.x, f0.x, f0.y);
                    CVTPK(u.y, f0.z, f0.w);
                    CVTPK(u.z, f1.x, f1.y);
                    CVTPK(u.w, f1.z, f1.w);
                    CVTPK(w.x, g0.x, g0.y);
                    CVTPK(w.y, g0.z, g0.w);
                    CVTPK(w.z, g1.x, g1.y);
                    CVTPK(w.w, g1.z, g1.w);
                    A0[kc] = *reinterpret_cast<bf16x8*>(&u);
                    A1[kc] = *reinterpret_cast<bf16x8*>(&w);
                }
            }
#pragma unroll
            for (int kc = 0; kc < KC; ++kc)
#pragma unroll
                for (int nt = 0; nt < 4; ++nt)
                    acc[nt] = __builtin_amdgcn_mfma_f32_16x16x32_bf16(
                        A0[kc], B[kc][nt], acc[nt], 0, 0, 0);
#pragma unroll
            for (int kc = 0; kc < KC; ++kc)
#pragma unroll
                for (int nt = 0; nt < 4; ++nt)
                    acc[nt] = __builtin_amdgcn_mfma_f32_16x16x32_bf16(
                        A1[kc], B[kc][nt], acc[nt], 0, 0, 0);
        }
    }

    // cross-wave reduce + epilogue (wave w handles ntiles 2w, 2w+1)
#pragma unroll
    for (int nt = 0; nt < 4; ++nt) red[wave][nt][lane] = acc[nt];
    __syncthreads();

#pragma unroll
    for (int t = 0; t < 2; ++t) {
        const int nt = wave * 2 + t;
        const f32x4 v4 = red[0][nt][lane] + red[1][nt][lane];
        const int col = nt * 16 + l15;
        float sum = 0.f, ssum = 0.f;
#pragma unroll
        for (int j = 0; j < 4; ++j) {
            const float v = v4[j];
            y[(size_t)(r0 + kgrp * 4 + j) * DCH + col] = v;
            sum += v;
            ssum += v * v;
        }
        sum  += __shfl_xor(sum, 16);  sum  += __shfl_xor(sum, 32);
        ssum += __shfl_xor(ssum, 16); ssum += __shfl_xor(ssum, 32);
        if (kgrp == 0) {
            unsafeAtomicAdd(&stats[col], sum);
            unsafeAtomicAdd(&stats[64 + col], ssum);
        }
    }
}

// BN+ReLU. MODE 0: fp32 in-place only. MODE 1: fp32 in-place + bf16 copy.
// MODE 2: bf16 copy ONLY (fp32 result dead downstream -- skip the store).
template <int MODE>
__global__ __launch_bounds__(256)
void bn_apply_kernel(float* __restrict__ x, uint* __restrict__ xb, int n_half,
                     const float* __restrict__ stats,
                     const float* __restrict__ g,
                     const float* __restrict__ b,
                     float inv_n)
{
    const int d0 = (threadIdx.x * 2) & 63;
    const float m0 = stats[d0] * inv_n,     m1 = stats[d0 + 1] * inv_n;
    const float v0 = stats[64 + d0] * inv_n - m0 * m0;
    const float v1 = stats[64 + d0 + 1] * inv_n - m1 * m1;
    const float sc0 = g[d0] * rsqrtf(v0 + BN_EPS), sc1 = g[d0 + 1] * rsqrtf(v1 + BN_EPS);
    const float sh0 = b[d0] - m0 * sc0,            sh1 = b[d0 + 1] - m1 * sc1;
    for (int i = blockIdx.x * 256 + threadIdx.x; i < n_half; i += gridDim.x * 256) {
        float2 v = reinterpret_cast<float2*>(x)[i];
        const float r0 = fmaxf(__builtin_fmaf(v.x, sc0, sh0), 0.f);
        const float r1 = fmaxf(__builtin_fmaf(v.y, sc1, sh1), 0.f);
        if (MODE != 2) reinterpret_cast<float2*>(x)[i] = make_float2(r0, r1);
        if (MODE >= 1) {
            uint u;
            CVTPK(u, r0, r1);
            xb[i] = u;
        }
    }
}

__global__ __launch_bounds__(256)
void bn_final_kernel(float* __restrict__ y2, const float* __restrict__ xnet,
                     int n_elem,
                     const float* __restrict__ stats,
                     const float* __restrict__ g,
                     const float* __restrict__ b,
                     float inv_n)
{
    const int d = threadIdx.x & 63;
    const float m   = stats[d] * inv_n;
    const float var = stats[64 + d] * inv_n - m * m;
    const float sc  = g[d] * rsqrtf(var + BN_EPS);
    const float sh  = b[d] - m * sc;
    for (int i = blockIdx.x * 256 + threadIdx.x; i < n_elem; i += gridDim.x * 256) {
        float v = y2[i];
        y2[i] = xnet[i] + fmaxf(__builtin_fmaf(v, sc, sh), 0.f);
    }
}

extern "C" void kernel_launch(void* const* d_in, const int* in_sizes, int n_in,
                              void* d_out, int out_size, void* d_ws, size_t ws_size,
                              hipStream_t stream)
{
    const float* feats  = (const float*)d_in[0];
    const float* W_down = (const float*)d_in[1];
    const float* g0     = (const float*)d_in[2];
    const float* b0     = (const float*)d_in[3];
    const float* W1     = (const float*)d_in[4];
    const float* g1     = (const float*)d_in[5];
    const float* b1     = (const float*)d_in[6];
    const float* W2     = (const float*)d_in[7];
    const float* g2     = (const float*)d_in[8];
    const float* b2     = (const float*)d_in[9];
    const int* pdi      = (const int*)d_in[10];
    const int* pdo      = (const int*)d_in[11];
    const int* psi      = (const int*)d_in[12];
    const int* pso      = (const int*)d_in[13];

    const int P1     = in_sizes[10] / K_TAPS;
    const int P2     = in_sizes[12] / K_TAPS;
    const int M1     = in_sizes[10];
    const int Nin    = in_sizes[0] / 32;
    const int n_out  = out_size / DCH;
    const int n_elem = n_out * DCH;
    const int NB     = n_out * K_TAPS;
    const float inv_n = 1.0f / (float)n_out;

    float* out = (float*)d_out;

    // ---- workspace layout (base ~29.6 MB, r13-proven) ----
    float* xnet  = (float*)d_ws;
    int*   counts = (int*)d_ws;
    uint*  rank_sm = (uint*)d_ws + NB;
    float* stats = xnet + (size_t)n_elem;
    int* S = (int*)(stats + 384);
    int* E = S + (NB + 1);
    int* partials = E + M1;              // M1 >= M2
    uint* Wp_dn = (uint*)(partials + 1024);
    uint* Wp_s1 = Wp_dn + 27 * 1 * 4 * 64 * 4;
    uint* Wp_s2 = Wp_s1 + 27 * 2 * 4 * 64 * 4;
    uint* rank_dn = (uint*)d_out;

    // optional bf16-input extension (gated on ws_size)
    uintptr_t pa = (uintptr_t)(Wp_s2 + 27 * 2 * 4 * 64 * 4);
    pa = (pa + 255) & ~(uintptr_t)255;
    uint* featsb = (uint*)pa;                       // Nin*32 bf16 = Nin*16 uints
    uint* x0b    = featsb + (size_t)Nin * 16;       // n_elem/2 uints
    uint* xnetb  = x0b + (size_t)n_elem / 2;        // n_elem/2 uints
    const size_t needed = (size_t)((char*)(xnetb + n_elem / 2) - (char*)d_ws);
    const bool bf16path = ws_size >= needed;

    float* st0 = stats;
    float* st1 = stats + 128;
    float* st2 = stats + 256;

    const dim3 blk(256);
    const dim3 cblk(128);
    const dim3 gridH1((P1 + 255) / 256, K_TAPS);
    const dim3 gridH2((P2 + 255) / 256, K_TAPS);
    const int nchunks = (NB + SCAN_CHUNK - 1) / SCAN_CHUNK;
    const int ewBlocks = 2048;
    const int convBlocks = (n_out + 15) / 16;   // 16 rows/block, 2 waves k-split

    hipMemsetAsync(stats, 0, sizeof(float) * 384, stream);

    // ---- W fragment pre-pack ----
    pack_w_kernel<<<81, blk, 0, stream>>>(W_down, W1, W2, Wp_dn, Wp_s1, Wp_s2);
    if (bf16path)
        f2bf_kernel<<<ewBlocks, blk, 0, stream>>>(feats, featsb, Nin * 16);

    // ---- build down CSR: rank -> scan -> scatter ----
    hipMemsetAsync(counts, 0, sizeof(int) * (size_t)NB, stream);
    rank_kernel<<<gridH1, blk, 0, stream>>>(pdo, P1, counts, rank_dn);
    scan_sum_kernel<<<nchunks, blk, 0, stream>>>(counts, NB, partials);
    scan_partials_kernel<<<1, 512, 0, stream>>>(partials, nchunks);
    scan_write_kernel<<<nchunks, blk, 0, stream>>>(counts, NB, partials, S);
    scatter_kernel<<<gridH1, blk, 0, stream>>>(pdi, rank_dn, P1, S, E);

    // ---- DownBlock ----
    if (bf16path) {
        mfma_conv_kernel<32, ushort><<<convBlocks, cblk, 0, stream>>>(
            (const ushort*)featsb, Wp_dn, S, E, out, st0, n_out);
        // x0 fp32 is dead after conv1 (conv1 reads x0b; d_out fully
        // rewritten by conv2 epilogue) -> bf16-only BN output (MODE 2)
        bn_apply_kernel<2><<<ewBlocks, blk, 0, stream>>>(out, x0b, n_elem / 2, st0, g0, b0, inv_n);
    } else {
        mfma_conv_kernel<32, float><<<convBlocks, cblk, 0, stream>>>(
            feats, Wp_dn, S, E, out, st0, n_out);
        bn_apply_kernel<0><<<ewBlocks, blk, 0, stream>>>(out, nullptr, n_elem / 2, st0, g0, b0, inv_n);
    }

    // ---- build subm CSR (down CSR dead) ----
    hipMemsetAsync(counts, 0, sizeof(int) * (size_t)NB, stream);
    rank_kernel<<<gridH2, blk, 0, stream>>>(pso, P2, counts, rank_sm);
    scan_sum_kernel<<<nchunks, blk, 0, stream>>>(counts, NB, partials);
    scan_partials_kernel<<<1, 512, 0, stream>>>(partials, nchunks);
    scan_write_kernel<<<nchunks, blk, 0, stream>>>(counts, NB, partials, S);
    scatter_kernel<<<gridH2, blk, 0, stream>>>(psi, rank_sm, P2, S, E);

    // ---- ResBlock conv1 ----
    if (bf16path) {
        mfma_conv_kernel<64, ushort><<<convBlocks, cblk, 0, stream>>>(
            (const ushort*)x0b, Wp_s1, S, E, xnet, st1, n_out);
        bn_apply_kernel<1><<<ewBlocks, blk, 0, stream>>>(xnet, xnetb, n_elem / 2, st1, g1, b1, inv_n);
    } else {
        mfma_conv_kernel<64, float><<<convBlocks, cblk, 0, stream>>>(
            out, Wp_s1, S, E, xnet, st1, n_out);
        bn_apply_kernel<0><<<ewBlocks, blk, 0, stream>>>(xnet, nullptr, n_elem / 2, st1, g1, b1, inv_n);
    }

    // ---- ResBlock conv2 ----
    if (bf16path)
        mfma_conv_kernel<64, ushort><<<convBlocks, cblk, 0, stream>>>(
            (const ushort*)xnetb, Wp_s2, S, E, out, st2, n_out);
    else
        mfma_conv_kernel<64, float><<<convBlocks, cblk, 0, stream>>>(
            xnet, Wp_s2, S, E, out, st2, n_out);

    // ---- out = x_net + relu(bn(y2)) ----
    bn_final_kernel<<<ewBlocks, blk, 0, stream>>>(out, xnet, n_elem, st2, g2, b2, inv_n);
}

// Round 20
// 664.232 us; speedup vs baseline: 2.2101x; 1.0106x over previous
//
#include <hip/hip_runtime.h>
#include <hip/hip_bf16.h>

#define K_TAPS 27
#define DCH 64
#define BN_EPS 1e-5f
#define SCAN_CHUNK 4096

typedef float f32x4 __attribute__((ext_vector_type(4)));
typedef short bf16x8 __attribute__((ext_vector_type(8)));
typedef unsigned int uint;
typedef unsigned short ushort;

// pack two f32 -> one dword of 2 bf16 (RNE); same instruction everywhere so
// rounding/order is consistent across pre-packed and in-kernel conversions.
#define CVTPK(dst, lo, hi) \
    asm("v_cvt_pk_bf16_f32 %0, %1, %2" : "=v"(dst) : "v"(lo), "v"(hi))

// ---------------------------------------------------------------------------
// CSR build pass A (fused hist+rank): returning atomic per pair, coalesced
// packed write: packed[i] = (bucket << 11) | rank_within_bucket.
// ---------------------------------------------------------------------------
__global__ __launch_bounds__(256)
void rank_kernel(const int* __restrict__ pout, int P,
                 int* __restrict__ counts, uint* __restrict__ packed)
{
    const int k = blockIdx.y;
    const int p = blockIdx.x * 256 + threadIdx.x;
    if (p < P) {
        const size_t i = (size_t)k * P + p;
        const int b = pout[i] * K_TAPS + k;
        const int r = atomicAdd(&counts[b], 1);
        packed[i] = ((uint)b << 11) | (uint)(r & 2047);
    }
}

__global__ __launch_bounds__(256)
void scan_sum_kernel(const int* __restrict__ counts, int n, int* __restrict__ partials)
{
    __shared__ int sm[256];
    const int base = blockIdx.x * SCAN_CHUNK;
    int s = 0;
#pragma unroll
    for (int j = 0; j < 16; ++j) {
        const int i = base + j * 256 + threadIdx.x;
        if (i < n) s += counts[i];
    }
    sm[threadIdx.x] = s;
    __syncthreads();
    for (int off = 128; off > 0; off >>= 1) {
        if (threadIdx.x < off) sm[threadIdx.x] += sm[threadIdx.x + off];
        __syncthreads();
    }
    if (threadIdx.x == 0) partials[blockIdx.x] = sm[0];
}

__global__ __launch_bounds__(512)
void scan_partials_kernel(int* __restrict__ partials, int n)
{
    __shared__ int sm[512];
    const int t = threadIdx.x;
    const int v = (t < n) ? partials[t] : 0;
    sm[t] = v;
    __syncthreads();
    for (int off = 1; off < 512; off <<= 1) {
        int tv = 0;
        if (t >= off) tv = sm[t - off];
        __syncthreads();
        if (t >= off) sm[t] += tv;
        __syncthreads();
    }
    if (t < n) partials[t] = sm[t] - v;  // exclusive
}

// S[i] = exclusive prefix (bucket start); S[n] = total.
__global__ __launch_bounds__(256)
void scan_write_kernel(const int* __restrict__ counts, int n,
                       const int* __restrict__ chunkoff, int* __restrict__ S)
{
    __shared__ int sm[256];
    const int base = blockIdx.x * SCAN_CHUNK + threadIdx.x * 16;
    int v[16];
    int s = 0;
#pragma unroll
    for (int j = 0; j < 16; ++j) {
        const int i = base + j;
        v[j] = (i < n) ? counts[i] : 0;
        s += v[j];
    }
    sm[threadIdx.x] = s;
    __syncthreads();
    for (int off = 1; off < 256; off <<= 1) {
        int tv = 0;
        if (threadIdx.x >= off) tv = sm[threadIdx.x - off];
        __syncthreads();
        if (threadIdx.x >= off) sm[threadIdx.x] += tv;
        __syncthreads();
    }
    int run = chunkoff[blockIdx.x] + sm[threadIdx.x] - s;  // exclusive base
#pragma unroll
    for (int j = 0; j < 16; ++j) {
        const int i = base + j;
        if (i < n) {
            S[i] = run;
            run += v[j];
            if (i == n - 1) S[n] = run;
        }
    }
}

// CSR build pass B (atomic-free scatter): E[S[b] + rank] = pin[i]
__global__ __launch_bounds__(256)
void scatter_kernel(const int* __restrict__ pin, const uint* __restrict__ packed,
                    int P, const int* __restrict__ S, int* __restrict__ E)
{
    const int k = blockIdx.y;
    const int p = blockIdx.x * 256 + threadIdx.x;
    if (p < P) {
        const size_t i = (size_t)k * P + p;
        const uint u = packed[i];
        E[S[u >> 11] + (int)(u & 2047u)] = pin[i];
    }
}

// ---------------------------------------------------------------------------
// W pre-pack into MFMA B-fragment layout, bf16 (CVTPK).
// Wp[k][kc][nt][lane][4 dwords]. blocks 0..26 Wd(C=32), 27..53 W1, 54..80 W2.
// ---------------------------------------------------------------------------
__global__ __launch_bounds__(256)
void pack_w_kernel(const float* __restrict__ Wd,
                   const float* __restrict__ W1,
                   const float* __restrict__ W2,
                   uint* __restrict__ Pd, uint* __restrict__ P1, uint* __restrict__ P2)
{
    int b = blockIdx.x;
    const float* W; uint* P; int C, k;
    if (b < 27)      { W = Wd; P = Pd; C = 32; k = b; }
    else if (b < 54) { W = W1; P = P1; C = 64; k = b - 27; }
    else             { W = W2; P = P2; C = 64; k = b - 54; }
    const int KC = C / 32;
    for (int t = threadIdx.x; t < KC * 4 * 64; t += 256) {
        const int l  = t & 63;
        const int nt = (t >> 6) & 3;
        const int kc = t >> 8;
        const int c0  = kc * 32 + ((l >> 4) << 3);
        const int col = nt * 16 + (l & 15);
        float f[8];
#pragma unroll
        for (int j = 0; j < 8; ++j)
            f[j] = W[((size_t)k * C + c0 + j) * DCH + col];
        uint4 u;
        CVTPK(u.x, f[0], f[1]);
        CVTPK(u.y, f[2], f[3]);
        CVTPK(u.z, f[4], f[5]);
        CVTPK(u.w, f[6], f[7]);
        *reinterpret_cast<uint4*>(P + ((size_t)((k * KC + kc) * 4 + nt) * 64 + l) * 4) = u;
    }
}

// fp32 -> packed bf16 (pairwise CVTPK, identical rounding to conv path)
__global__ __launch_bounds__(256)
void f2bf_kernel(const float* __restrict__ in, uint* __restrict__ out, int n_half)
{
    for (int i = blockIdx.x * 256 + threadIdx.x; i < n_half; i += gridDim.x * 256) {
        const float2 v = reinterpret_cast<const float2*>(in)[i];
        uint u;
        CVTPK(u, v.x, v.y);
        out[i] = u;
    }
}

// ---------------------------------------------------------------------------
// Implicit-GEMM gather conv, v5 (r15/r18 structure, best measured & twice
// reproduced: 665/671us total). 2-wave k-split, slot UNROLL-2, LB(128,5):
// the 102-reg budget covers the ~68 unified VGPR+AGPR live set. Proven
// failure modes of alternatives: unroll-4 (r16) and LB(128,8) (r17) spill
// the unified file (0.5-1.4GB scratch traffic); 2-wave n-split (r19)
// produced wrong results (suspected backend codegen issue).
// ---------------------------------------------------------------------------
template <int C, typename T>
__global__ __launch_bounds__(128, 5)
void mfma_conv_kernel(const T* __restrict__ x,
                      const uint* __restrict__ Wp,
                      const int* __restrict__ S,
                      const int* __restrict__ E,
                      float* __restrict__ y,
                      float* __restrict__ stats,
                      int n_out)
{
    constexpr int KC = C / 32;
    constexpr int SN = 16 * K_TAPS + 1;   // 433
    const int tid  = threadIdx.x;
    const int lane = tid & 63;
    const int wave = tid >> 6;            // 0,1
    const int r0 = blockIdx.x * 16;
    if (r0 >= n_out) return;

    __shared__ int sS[SN];
    __shared__ f32x4 red[2][4][64];

    for (int i = tid; i < SN; i += 128) sS[i] = S[r0 * K_TAPS + i];
    __syncthreads();

    const int l15  = lane & 15;
    const int kgrp = lane >> 4;
    const int koff = kgrp * 8;

    f32x4 acc[4];
#pragma unroll
    for (int nt = 0; nt < 4; ++nt) acc[nt] = (f32x4)0.f;

    for (int k = wave; k < K_TAPS; k += 2) {
        bf16x8 B[KC][4];
#pragma unroll
        for (int kc = 0; kc < KC; ++kc)
#pragma unroll
            for (int nt = 0; nt < 4; ++nt)
                B[kc][nt] = *reinterpret_cast<const bf16x8*>(
                    Wp + ((size_t)((k * KC + kc) * 4 + nt) * 64 + lane) * 4);

        const int e1 = sS[l15 * K_TAPS + k + 1];
        for (int s = sS[l15 * K_TAPS + k]; ; s += 2) {
            const bool a0 = s < e1;
            const bool a1 = s + 1 < e1;
            if (!__any(a0)) break;
            // issue both E loads, then both gathers (2 chains in flight)
            const int ir0 = a0 ? E[s] : 0;
            const int ir1 = a1 ? E[s + 1] : 0;
            bf16x8 A0[KC], A1[KC];
#pragma unroll
            for (int kc = 0; kc < KC; ++kc) {
                if constexpr (sizeof(T) == 2) {
                    bf16x8 v0 = (bf16x8)0, v1 = (bf16x8)0;
                    if (a0) v0 = *reinterpret_cast<const bf16x8*>(
                        (const ushort*)x + (size_t)ir0 * C + kc * 32 + koff);
                    if (a1) v1 = *reinterpret_cast<const bf16x8*>(
                        (const ushort*)x + (size_t)ir1 * C + kc * 32 + koff);
                    A0[kc] = v0;
                    A1[kc] = v1;
                } else {
                    float4 f0 = {0.f, 0.f, 0.f, 0.f}, f1 = {0.f, 0.f, 0.f, 0.f};
                    float4 g0 = {0.f, 0.f, 0.f, 0.f}, g1 = {0.f, 0.f, 0.f, 0.f};
                    if (a0) {
                        const float4* fp = reinterpret_cast<const float4*>(
                            (const float*)x + (size_t)ir0 * C + kc * 32 + koff);
                        f0 = fp[0];
                        f1 = fp[1];
                    }
                    if (a1) {
                        const float4* gp = reinterpret_cast<const float4*>(
                            (const float*)x + (size_t)ir1 * C + kc * 32 + koff);
                        g0 = gp[0];
                        g1 = gp[1];
                    }
                    uint4 u, w;
                    CVTPK(u.x, f0.x, f0.y);
                    CVTPK(u.y, f0.z, f0.w);
                    CVTPK(u.z, f1.x, f1.y);
                    CVTPK(u.w, f1.z, f1.w);
                    CVTPK(w.x, g0.x, g0.y);
                    CVTPK(w.y, g0.z, g0.w);
                    CVTPK(w.z, g1.x, g1.y);
                    CVTPK(w.w, g1.z, g1.w);
                    A0[kc] = *reinterpret_cast<bf16x8*>(&u);
                    A1[kc] = *reinterpret_cast<bf16x8*>(&w);
                }
            }
#pragma unroll
            for (int kc = 0; kc < KC; ++kc)
#pragma unroll
                for (int nt = 0; nt < 4; ++nt)
                    acc[nt] = __builtin_amdgcn_mfma_f32_16x16x32_bf16(
                        A0[kc], B[kc][nt], acc[nt], 0, 0, 0);
#pragma unroll
            for (int kc = 0; kc < KC; ++kc)
#pragma unroll
                for (int nt = 0; nt < 4; ++nt)
                    acc[nt] = __builtin_amdgcn_mfma_f32_16x16x32_bf16(
                        A1[kc], B[kc][nt], acc[nt], 0, 0, 0);
        }
    }

    // cross-wave reduce + epilogue (wave w handles ntiles 2w, 2w+1)
#pragma unroll
    for (int nt = 0; nt < 4; ++nt) red[wave][nt][lane] = acc[nt];
    __syncthreads();

#pragma unroll
    for (int t = 0; t < 2; ++t) {
        const int nt = wave * 2 + t;
        const f32x4 v4 = red[0][nt][lane] + red[1][nt][lane];
        const int col = nt * 16 + l15;
        float sum = 0.f, ssum = 0.f;
#pragma unroll
        for (int j = 0; j < 4; ++j) {
            const float v = v4[j];
            y[(size_t)(r0 + kgrp * 4 + j) * DCH + col] = v;
            sum += v;
            ssum += v * v;
        }
        sum  += __shfl_xor(sum, 16);  sum  += __shfl_xor(sum, 32);
        ssum += __shfl_xor(ssum, 16); ssum += __shfl_xor(ssum, 32);
        if (kgrp == 0) {
            unsafeAtomicAdd(&stats[col], sum);
            unsafeAtomicAdd(&stats[64 + col], ssum);
        }
    }
}

// BN+ReLU. MODE 0: fp32 in-place only. MODE 1: fp32 in-place + bf16 copy.
// MODE 2: bf16 copy ONLY (fp32 result dead downstream -- skip the store).
template <int MODE>
__global__ __launch_bounds__(256)
void bn_apply_kernel(float* __restrict__ x, uint* __restrict__ xb, int n_half,
                     const float* __restrict__ stats,
                     const float* __restrict__ g,
                     const float* __restrict__ b,
                     float inv_n)
{
    const int d0 = (threadIdx.x * 2) & 63;
    const float m0 = stats[d0] * inv_n,     m1 = stats[d0 + 1] * inv_n;
    const float v0 = stats[64 + d0] * inv_n - m0 * m0;
    const float v1 = stats[64 + d0 + 1] * inv_n - m1 * m1;
    const float sc0 = g[d0] * rsqrtf(v0 + BN_EPS), sc1 = g[d0 + 1] * rsqrtf(v1 + BN_EPS);
    const float sh0 = b[d0] - m0 * sc0,            sh1 = b[d0 + 1] - m1 * sc1;
    for (int i = blockIdx.x * 256 + threadIdx.x; i < n_half; i += gridDim.x * 256) {
        float2 v = reinterpret_cast<float2*>(x)[i];
        const float r0 = fmaxf(__builtin_fmaf(v.x, sc0, sh0), 0.f);
        const float r1 = fmaxf(__builtin_fmaf(v.y, sc1, sh1), 0.f);
        if (MODE != 2) reinterpret_cast<float2*>(x)[i] = make_float2(r0, r1);
        if (MODE >= 1) {
            uint u;
            CVTPK(u, r0, r1);
            xb[i] = u;
        }
    }
}

__global__ __launch_bounds__(256)
void bn_final_kernel(float* __restrict__ y2, const float* __restrict__ xnet,
                     int n_elem,
                     const float* __restrict__ stats,
                     const float* __restrict__ g,
                     const float* __restrict__ b,
                     float inv_n)
{
    const int d = threadIdx.x & 63;
    const float m   = stats[d] * inv_n;
    const float var = stats[64 + d] * inv_n - m * m;
    const float sc  = g[d] * rsqrtf(var + BN_EPS);
    const float sh  = b[d] - m * sc;
    for (int i = blockIdx.x * 256 + threadIdx.x; i < n_elem; i += gridDim.x * 256) {
        float v = y2[i];
        y2[i] = xnet[i] + fmaxf(__builtin_fmaf(v, sc, sh), 0.f);
    }
}

extern "C" void kernel_launch(void* const* d_in, const int* in_sizes, int n_in,
                              void* d_out, int out_size, void* d_ws, size_t ws_size,
                              hipStream_t stream)
{
    const float* feats  = (const float*)d_in[0];
    const float* W_down = (const float*)d_in[1];
    const float* g0     = (const float*)d_in[2];
    const float* b0     = (const float*)d_in[3];
    const float* W1     = (const float*)d_in[4];
    const float* g1     = (const float*)d_in[5];
    const float* b1     = (const float*)d_in[6];
    const float* W2     = (const float*)d_in[7];
    const float* g2     = (const float*)d_in[8];
    const float* b2     = (const float*)d_in[9];
    const int* pdi      = (const int*)d_in[10];
    const int* pdo      = (const int*)d_in[11];
    const int* psi      = (const int*)d_in[12];
    const int* pso      = (const int*)d_in[13];

    const int P1     = in_sizes[10] / K_TAPS;
    const int P2     = in_sizes[12] / K_TAPS;
    const int M1     = in_sizes[10];
    const int Nin    = in_sizes[0] / 32;
    const int n_out  = out_size / DCH;
    const int n_elem = n_out * DCH;
    const int NB     = n_out * K_TAPS;
    const float inv_n = 1.0f / (float)n_out;

    float* out = (float*)d_out;

    // ---- workspace layout (base ~29.6 MB, r13-proven) ----
    float* xnet  = (float*)d_ws;
    int*   counts = (int*)d_ws;
    uint*  rank_sm = (uint*)d_ws + NB;
    float* stats = xnet + (size_t)n_elem;
    int* S = (int*)(stats + 384);
    int* E = S + (NB + 1);
    int* partials = E + M1;              // M1 >= M2
    uint* Wp_dn = (uint*)(partials + 1024);
    uint* Wp_s1 = Wp_dn + 27 * 1 * 4 * 64 * 4;
    uint* Wp_s2 = Wp_s1 + 27 * 2 * 4 * 64 * 4;
    uint* rank_dn = (uint*)d_out;

    // optional bf16-input extension (gated on ws_size)
    uintptr_t pa = (uintptr_t)(Wp_s2 + 27 * 2 * 4 * 64 * 4);
    pa = (pa + 255) & ~(uintptr_t)255;
    uint* featsb = (uint*)pa;                       // Nin*32 bf16 = Nin*16 uints
    uint* x0b    = featsb + (size_t)Nin * 16;       // n_elem/2 uints
    uint* xnetb  = x0b + (size_t)n_elem / 2;        // n_elem/2 uints
    const size_t needed = (size_t)((char*)(xnetb + n_elem / 2) - (char*)d_ws);
    const bool bf16path = ws_size >= needed;

    float* st0 = stats;
    float* st1 = stats + 128;
    float* st2 = stats + 256;

    const dim3 blk(256);
    const dim3 cblk(128);
    const dim3 gridH1((P1 + 255) / 256, K_TAPS);
    const dim3 gridH2((P2 + 255) / 256, K_TAPS);
    const int nchunks = (NB + SCAN_CHUNK - 1) / SCAN_CHUNK;
    const int ewBlocks = 2048;
    const int convBlocks = (n_out + 15) / 16;   // 16 rows/block, 2 waves k-split

    hipMemsetAsync(stats, 0, sizeof(float) * 384, stream);

    // ---- W fragment pre-pack ----
    pack_w_kernel<<<81, blk, 0, stream>>>(W_down, W1, W2, Wp_dn, Wp_s1, Wp_s2);
    if (bf16path)
        f2bf_kernel<<<ewBlocks, blk, 0, stream>>>(feats, featsb, Nin * 16);

    // ---- build down CSR: rank -> scan -> scatter ----
    hipMemsetAsync(counts, 0, sizeof(int) * (size_t)NB, stream);
    rank_kernel<<<gridH1, blk, 0, stream>>>(pdo, P1, counts, rank_dn);
    scan_sum_kernel<<<nchunks, blk, 0, stream>>>(counts, NB, partials);
    scan_partials_kernel<<<1, 512, 0, stream>>>(partials, nchunks);
    scan_write_kernel<<<nchunks, blk, 0, stream>>>(counts, NB, partials, S);
    scatter_kernel<<<gridH1, blk, 0, stream>>>(pdi, rank_dn, P1, S, E);

    // ---- DownBlock ----
    if (bf16path) {
        mfma_conv_kernel<32, ushort><<<convBlocks, cblk, 0, stream>>>(
            (const ushort*)featsb, Wp_dn, S, E, out, st0, n_out);
        // x0 fp32 is dead after conv1 (conv1 reads x0b; d_out fully
        // rewritten by conv2 epilogue) -> bf16-only BN output (MODE 2)
        bn_apply_kernel<2><<<ewBlocks, blk, 0, stream>>>(out, x0b, n_elem / 2, st0, g0, b0, inv_n);
    } else {
        mfma_conv_kernel<32, float><<<convBlocks, cblk, 0, stream>>>(
            feats, Wp_dn, S, E, out, st0, n_out);
        bn_apply_kernel<0><<<ewBlocks, blk, 0, stream>>>(out, nullptr, n_elem / 2, st0, g0, b0, inv_n);
    }

    // ---- build subm CSR (down CSR dead) ----
    hipMemsetAsync(counts, 0, sizeof(int) * (size_t)NB, stream);
    rank_kernel<<<gridH2, blk, 0, stream>>>(pso, P2, counts, rank_sm);
    scan_sum_kernel<<<nchunks, blk, 0, stream>>>(counts, NB, partials);
    scan_partials_kernel<<<1, 512, 0, stream>>>(partials, nchunks);
    scan_write_kernel<<<nchunks, blk, 0, stream>>>(counts, NB, partials, S);
    scatter_kernel<<<gridH2, blk, 0, stream>>>(psi, rank_sm, P2, S, E);

    // ---- ResBlock conv1 ----
    if (bf16path) {
        mfma_conv_kernel<64, ushort><<<convBlocks, cblk, 0, stream>>>(
            (const ushort*)x0b, Wp_s1, S, E, xnet, st1, n_out);
        bn_apply_kernel<1><<<ewBlocks, blk, 0, stream>>>(xnet, xnetb, n_elem / 2, st1, g1, b1, inv_n);
    } else {
        mfma_conv_kernel<64, float><<<convBlocks, cblk, 0, stream>>>(
            out, Wp_s1, S, E, xnet, st1, n_out);
        bn_apply_kernel<0><<<ewBlocks, blk, 0, stream>>>(xnet, nullptr, n_elem / 2, st1, g1, b1, inv_n);
    }

    // ---- ResBlock conv2 ----
    if (bf16path)
        mfma_conv_kernel<64, ushort><<<convBlocks, cblk, 0, stream>>>(
            (const ushort*)xnetb, Wp_s2, S, E, out, st2, n_out);
    else
        mfma_conv_kernel<64, float><<<convBlocks, cblk, 0, stream>>>(
            xnet, Wp_s2, S, E, out, st2, n_out);

    // ---- out = x_net + relu(bn(y2)) ----
    bn_final_kernel<<<ewBlocks, blk, 0, stream>>>(out, xnet, n_elem, st2, g2, b2, inv_n);
}